// Round 5
// baseline (20.601 us; speedup 1.0000x reference)
//
#include <hip/hip_runtime.h>
#include <math.h>

#define NCLS 20
#define B_N 128
#define A_N 5
#define H_N 26
#define W_N 26
#define HW_N (H_N * W_N)            // 676
#define M_N 64
#define CH_N (5 + NCLS)             // 25
#define HALF_LOC (HW_N / 2)         // 338 locations per half-plane
#define HALF_T (HALF_LOC / 2)       // 169 active threads (2 locs each)
#define BLK_T 192                   // 3 waves
#define WAVES_PB 3
#define WIN_BLKS B_N                // 128 winner blocks (first in grid)
#define NOOBJ_BLKS (B_N * A_N * 2)  // 1280 half-plane blocks
#define SLOTS (NOOBJ_BLKS * WAVES_PB)  // 3840 per-wave partial slots
#define SLOTS_PER_B (A_N * 2 * WAVES_PB)  // 30 contiguous slots per batch

#define SENT 1.0e18f

__device__ __forceinline__ float fastrcp(float x) { return __builtin_amdgcn_rcpf(x); }
__device__ __forceinline__ float sigmoidf_(float x) { return fastrcp(1.0f + __expf(-x)); }

// ---------------------------------------------------------------------------
// Main kernel: 128 winner blocks + 1280 noobj half-plane blocks.
// NO __syncthreads anywhere: each wave stages its own LDS gt copy.
// All output slots written unconditionally -> no memset, deterministic.
// ---------------------------------------------------------------------------
__global__ __launch_bounds__(BLK_T) void main_kernel(
    const float* __restrict__ outputs, const float* __restrict__ targets,
    const float* __restrict__ anchors,
    float* __restrict__ A_part, float* __restrict__ H_part,
    int* __restrict__ any_part,
    float* __restrict__ Gb, float* __restrict__ Asub, float* __restrict__ Hsub,
    int* __restrict__ nobjArr) {
    int blk = blockIdx.x;
    bool winnerBlk = (blk < WIN_BLKS);
    int tid = threadIdx.x;
    if (winnerBlk && tid >= M_N) return;   // winner blocks: wave 0 only
    int w = tid >> 6, lane = tid & 63;
    int nb = blk - WIN_BLKS;
    int plane = nb >> 1, half = nb & 1;
    int b = winnerBlk ? blk : (plane / A_N);
    int a = winnerBlk ? 0 : (plane % A_N);

    __shared__ float4 sg4[WAVES_PB * M_N];     // per-wave gt copies
    __shared__ int owner[HW_N * A_N];          // winner-resolution table (13.5 KB)

    // ---- 1. issue target-row load (every lane owns row m = lane) ----
    const float* trow = targets + ((size_t)b * M_N + lane) * 5;
    float tc = trow[0], tx = trow[1], ty = trow[2], tw = trow[3], th = trow[4];

    // ---- 2. issue O-plane loads immediately (overlap with staging) ----
    float2 O0, O1, O2, O3, O4;
    int hw0 = 0;
    bool act = false;
    if (!winnerBlk) {
        act = (tid < HALF_T);
        if (act) {
            hw0 = half * HALF_LOC + tid * 2;
            const float* op = outputs +
                ((size_t)b * (A_N * CH_N) + (size_t)a * CH_N) * HW_N + hw0;
            O0 = *(const float2*)(op + 0 * HW_N);
            O1 = *(const float2*)(op + 1 * HW_N);
            O2 = *(const float2*)(op + 2 * HW_N);
            O3 = *(const float2*)(op + 3 * HW_N);
            O4 = *(const float2*)(op + 4 * HW_N);
        }
    }

    // ---- 3. validity, box build, stage into THIS wave's LDS copy ----
    bool valid = (tc + tx + ty + tw + th) > 0.0f;   // valid rows are a prefix
    unsigned long long mask = __ballot(valid);
    int nobj = __popcll(mask);
    int nobj8 = (nobj + 7) & ~7;
    float gx = tx * (float)W_N, gy = ty * (float)H_N;
    float gw = tw * (float)W_N, gh = th * (float)H_N;
    float4 g4 = valid ? make_float4(gx - gw * 0.5f, gy - gh * 0.5f,
                                    gx + gw * 0.5f, gy + gh * 0.5f)
                      : make_float4(SENT, SENT, SENT, SENT);
    // sentinel: inter clamps to 0, ga = (S-S)*(S-S) = 0 -> no effect on max/H/any
    float4* myg = sg4 + w * M_N;
    myg[lane] = g4;
    __threadfence_block();   // LDS writes visible to this wave's reads

    if (winnerBlk) {
        // ================= winner path (wave 0, lane == m) =================
        float G = 0.0f, c2A = 0.0f, c2H = 0.0f;
        int m = lane;
        int cell = (int)floorf(gy) * W_N + (int)floorf(gx);
        cell = min(max(cell, 0), HW_N - 1);
        int ccx = cell % W_N, ccy = cell / W_N;
        float best = -1.0f;
        int ai = 0; float aw = 1.0f, ah = 1.0f;
        float ga = gw * gh;
        #pragma unroll
        for (int aa = 0; aa < A_N; ++aa) {
            float anw = anchors[2 * aa], anh = anchors[2 * aa + 1];
            float atlx = (float)ccx + 0.5f - anw * 0.5f;
            float atly = (float)ccy + 0.5f - anh * 0.5f;
            float ix = fminf(atlx + anw, g4.z) - fmaxf(atlx, g4.x);
            float iy = fminf(atly + anh, g4.w) - fmaxf(atly, g4.y);
            float inter = fmaxf(ix, 0.0f) * fmaxf(iy, 0.0f);
            float ov = inter * fastrcp(anw * anh + ga - inter);
            if (ov > best) { best = ov; ai = aa; aw = anw; ah = anh; }
        }
        int mykey = cell * A_N + ai;

        // winner = largest valid m with this key (lax.scan overwrite semantics)
        if (valid) owner[mykey] = 0;
        __threadfence_block();
        if (valid) atomicMax(&owner[mykey], m);
        __threadfence_block();
        bool winner = valid && (owner[mykey] == m);

        if (winner) {
            size_t obase = ((size_t)b * (A_N * CH_N) + (size_t)ai * CH_N) * HW_N + cell;
            float o0 = outputs[obase + 0 * HW_N];
            float o1 = outputs[obase + 1 * HW_N];
            float o2 = outputs[obase + 2 * HW_N];
            float o3 = outputs[obase + 3 * HW_N];
            float o4 = outputs[obase + 4 * HW_N];
            float sx = sigmoidf_(o0), sy = sigmoidf_(o1);
            float ew = __expf(o2), eh = __expf(o3);
            float conf = sigmoidf_(o4);
            float px = sx + (float)ccx, py = sy + (float)ccy;
            float pw = ew * aw, ph = eh * ah;
            float ptlx = px - pw * 0.5f, ptly = py - ph * 0.5f;
            float pbrx = px + pw * 0.5f, pbry = py + ph * 0.5f;
            float pa = pw * ph;

            float mi = 0.0f, maxdW = -1e30f;
            #pragma unroll 4
            for (int mm = 0; mm < nobj8; ++mm) {
                float4 g = myg[mm];
                float gaM = (g.z - g.x) * (g.w - g.y);
                float ix = fminf(pbrx, g.z) - fmaxf(ptlx, g.x);
                float iy = fminf(pbry, g.w) - fmaxf(ptly, g.y);
                float inter = fmaxf(ix, 0.0f) * fmaxf(iy, 0.0f);
                mi = fmaxf(mi, inter * fastrcp(pa + gaM - inter));
                maxdW = fmaxf(maxdW, fmaf(3.0f, inter, -(pa + gaM)));
            }

            float dcf = conf - mi;
            G = dcf * dcf;
            float bs = 2.0f - (pw / (float)W_N) * (ph / (float)H_N);
            float e0 = sx - (gx - (float)ccx);
            float e1 = sy - (gy - (float)ccy);
            float e2 = ew - gw / aw;
            float e3 = eh - gh / ah;
            G += bs * (e0 * e0 + e1 * e1 + e2 * e2 + e3 * e3);

            int cls = (int)tc;
            float mx = -1e30f, tv = 0.0f, logits[NCLS];
            #pragma unroll
            for (int c = 0; c < NCLS; ++c) {
                logits[c] = outputs[obase + (size_t)(5 + c) * HW_N];
                mx = fmaxf(mx, logits[c]);
            }
            float se = 0.0f;
            #pragma unroll
            for (int c = 0; c < NCLS; ++c) {
                se += __expf(logits[c] - mx);
                if (c == cls) tv = logits[c];
            }
            G += (mx + __logf(se)) - tv;

            c2A = conf * conf;                       // noobj-sum corrections
            c2H = (maxdW >= 0.0f) ? c2A : 0.0f;      // same algebra as noobj pass
        }
        // deterministic wave reduction
        #pragma unroll
        for (int off = 32; off > 0; off >>= 1) {
            G   += __shfl_down(G, off);
            c2A += __shfl_down(c2A, off);
            c2H += __shfl_down(c2H, off);
        }
        if (lane == 0) {
            Gb[b] = G; Asub[b] = c2A; Hsub[b] = c2H; nobjArr[b] = nobj;
        }
    } else {
        // ================= noobj path: 2 locations per thread ==============
        float locA = 0.0f, locH = 0.0f;
        bool any = false;
        if (act) {
            int wy = hw0 / W_N;
            int wx = hw0 - wy * W_N;        // hw0 even, W even -> same row
            float aw = anchors[2 * a], ah = anchors[2 * a + 1];

            float sx0 = sigmoidf_(O0.x), sx1 = sigmoidf_(O0.y);
            float sy0 = sigmoidf_(O1.x), sy1 = sigmoidf_(O1.y);
            float pw0 = __expf(O2.x) * aw, pw1 = __expf(O2.y) * aw;
            float ph0 = __expf(O3.x) * ah, ph1 = __expf(O3.y) * ah;
            float px0 = sx0 + (float)wx, px1 = sx1 + (float)(wx + 1);
            float py0 = sy0 + (float)wy, py1 = sy1 + (float)wy;

            float ptlx0 = px0 - pw0 * 0.5f, ptly0 = py0 - ph0 * 0.5f;
            float pbrx0 = px0 + pw0 * 0.5f, pbry0 = py0 + ph0 * 0.5f;
            float ptlx1 = px1 - pw1 * 0.5f, ptly1 = py1 - ph1 * 0.5f;
            float pbrx1 = px1 + pw1 * 0.5f, pbry1 = py1 + ph1 * 0.5f;
            float pa0 = pw0 * ph0, pa1 = pw1 * ph1;

            // iou >= 0.5 <=> 3*inter - (pa+ga) >= 0 ; strict > for has_pos
            float maxd0 = -1e30f, maxd1 = -1e30f;
            for (int m = 0; m < nobj8; m += 8) {
                #pragma unroll
                for (int k = 0; k < 8; ++k) {
                    float4 g = myg[m + k];
                    float ga = (g.z - g.x) * (g.w - g.y);
                    float ix0 = fminf(pbrx0, g.z) - fmaxf(ptlx0, g.x);
                    float iy0 = fminf(pbry0, g.w) - fmaxf(ptly0, g.y);
                    float in0 = fmaxf(ix0, 0.0f) * fmaxf(iy0, 0.0f);
                    maxd0 = fmaxf(maxd0, fmaf(3.0f, in0, -(pa0 + ga)));
                    float ix1 = fminf(pbrx1, g.z) - fmaxf(ptlx1, g.x);
                    float iy1 = fminf(pbry1, g.w) - fmaxf(ptly1, g.y);
                    float in1 = fmaxf(ix1, 0.0f) * fmaxf(iy1, 0.0f);
                    maxd1 = fmaxf(maxd1, fmaf(3.0f, in1, -(pa1 + ga)));
                }
            }
            float conf0 = sigmoidf_(O4.x), conf1 = sigmoidf_(O4.y);
            float c20 = conf0 * conf0, c21 = conf1 * conf1;
            locA = c20 + c21;
            locH = (maxd0 >= 0.0f ? c20 : 0.0f) + (maxd1 >= 0.0f ? c21 : 0.0f);
            any = (maxd0 > 0.0f) || (maxd1 > 0.0f);
        }

        // per-wave deterministic reduction; each wave writes its own slot
        int wany = __any(any) ? 1 : 0;
        #pragma unroll
        for (int off = 32; off > 0; off >>= 1) {
            locA += __shfl_down(locA, off);
            locH += __shfl_down(locH, off);
        }
        if (lane == 0) {
            int slot = nb * WAVES_PB + w;
            A_part[slot] = locA;
            H_part[slot] = locH;
            any_part[slot] = wany;
        }
    }
}

// ---------------------------------------------------------------------------
// Finish: 128 threads, one per batch; fixed-order deterministic reduction.
// Batch b's 30 partial slots are contiguous: [b*30, b*30+30).
// ---------------------------------------------------------------------------
__global__ __launch_bounds__(128) void finish_kernel(
    const float* __restrict__ A_part, const float* __restrict__ H_part,
    const int* __restrict__ any_part,
    const float* __restrict__ Gb, const float* __restrict__ Asub,
    const float* __restrict__ Hsub, const int* __restrict__ nobjArr,
    float* __restrict__ out) {
    int t = threadIdx.x;  // == b
    float A = -Asub[t], Hs = -Hsub[t];
    int any = 0;
    #pragma unroll
    for (int j = 0; j < SLOTS_PER_B; ++j) {
        A += A_part[t * SLOTS_PER_B + j];
        Hs += H_part[t * SLOTS_PER_B + j];
        any |= any_part[t * SLOTS_PER_B + j];
    }
    float noobj = (nobjArr[t] > 0) ? (A - (any ? Hs : 0.0f)) : 0.0f;
    float v = Gb[t] + noobj;
    #pragma unroll
    for (int off = 32; off > 0; off >>= 1) v += __shfl_down(v, off);
    __shared__ float r[2];
    if ((t & 63) == 0) r[t >> 6] = v;
    __syncthreads();
    if (t == 0) out[0] = (r[0] + r[1]) / (float)B_N;
}

extern "C" void kernel_launch(void* const* d_in, const int* in_sizes, int n_in,
                              void* d_out, int out_size, void* d_ws, size_t ws_size,
                              hipStream_t stream) {
    const float* outputs = (const float*)d_in[0];
    const float* targets = (const float*)d_in[1];
    const float* anchors = (const float*)d_in[2];
    float* out = (float*)d_out;

    char* ws = (char*)d_ws;
    size_t off = 0;
    float* A_part = (float*)(ws + off); off += 4 * (size_t)SLOTS;
    float* H_part = (float*)(ws + off); off += 4 * (size_t)SLOTS;
    int* any_part = (int*)(ws + off);   off += 4 * (size_t)SLOTS;
    float* Gb = (float*)(ws + off);     off += 4 * B_N;
    float* Asub = (float*)(ws + off);   off += 4 * B_N;
    float* Hsub = (float*)(ws + off);   off += 4 * B_N;
    int* nobjArr = (int*)(ws + off);    off += 4 * B_N;
    // every slot above is unconditionally written each call -> no memset needed

    main_kernel<<<WIN_BLKS + NOOBJ_BLKS, BLK_T, 0, stream>>>(
        outputs, targets, anchors,
        A_part, H_part, any_part, Gb, Asub, Hsub, nobjArr);

    finish_kernel<<<1, 128, 0, stream>>>(A_part, H_part, any_part,
                                         Gb, Asub, Hsub, nobjArr, out);
}